// Round 18
// baseline (61.813 us; speedup 1.0000x reference)
//
#include <hip/hip_runtime.h>
#include <hip/hip_bf16.h>

#define S_LEN 4096
#define DHEAD 64
#define KBLK 64
#define CSZ 8          // k-tiles per chunk (512 kv positions)
#define NS 8           // max chunks per q-tile column
#define FM 12.0f       // fixed softmax base (log2 domain); cancels in final divide

typedef __attribute__((ext_vector_type(8))) short bf16x8;
typedef __attribute__((ext_vector_type(8))) unsigned short u16x8;
typedef __attribute__((ext_vector_type(4))) float f32x4;

__device__ __forceinline__ unsigned short f2bf(float f) {
    union { float f; unsigned u; } v; v.f = f;
    unsigned r = v.u + 0x7fffu + ((v.u >> 16) & 1u);   // RNE
    return (unsigned short)(r >> 16);
}

__device__ __forceinline__ float bf2f(unsigned short h) {
    union { unsigned u; float f; } v; v.u = ((unsigned)h) << 16; return v.f;
}

__device__ __forceinline__ unsigned pack_bf2(float a, float b) {
    __hip_bfloat162 h = __float22bfloat162_rn(float2{a, b});
    union { __hip_bfloat162 h; unsigned u; } cv; cv.h = h;
    return cv.u;
}

// raw 2^x — v_exp_f32; -inf -> 0 natively.
__device__ __forceinline__ float exp2_raw(float x) {
    float r;
    asm volatile("v_exp_f32 %0, %1\n\ts_nop 0" : "=v"(r) : "v"(x));
    return r;
}

// ---------------------------------------------------------------------------
// Prepass: frag-major bf16 blob. Per tile (16 KB = 8192 ushorts):
//   K-frag f=ct*2+kk at f*512 + lane*8 : K[ct*16+l15][kk*32+l4*8+j]
//   V-frag f=t*2+kk at 4096 + f*512 + lane*8 :
//        V[(2*((j>>2)&1)+kk)*16 + l4*4 + (j&3)][t*16+l15]   (sigma baked in)
// Plus bias table Mb[tile][64] = mask ? -FM : -inf.
// ---------------------------------------------------------------------------
__global__ __launch_bounds__(256) void prep(
        const float* __restrict__ K, const float* __restrict__ V,
        const int* __restrict__ mask,
        unsigned short* __restrict__ Tb, float* __restrict__ Mb)
{
    const int tile = blockIdx.x;            // b*64 + kt
    const int b = tile >> 6, kt = tile & 63;
    const float* kp = K + ((size_t)(b * S_LEN + kt * KBLK)) * DHEAD;
    const float* vp = V + ((size_t)(b * S_LEN + kt * KBLK)) * DHEAD;
    unsigned short* tb = Tb + (size_t)tile * 8192;
    const int tid = threadIdx.x;

    #pragma unroll
    for (int r = 0; r < 4; ++r) {
        int c16 = r * 256 + tid;            // 16B chunk id, 0..1023
        int lane = c16 & 63, f = (c16 >> 6) & 7, half = c16 >> 9;
        int l15 = lane & 15, l4 = lane >> 4;
        u16x8 o;
        if (half == 0) {
            int ct = f >> 1, kk = f & 1;
            const float* src = kp + (ct * 16 + l15) * DHEAD + kk * 32 + l4 * 8;
            float4 a = *(const float4*)src;
            float4 c2 = *(const float4*)(src + 4);
            o[0] = f2bf(a.x); o[1] = f2bf(a.y); o[2] = f2bf(a.z); o[3] = f2bf(a.w);
            o[4] = f2bf(c2.x); o[5] = f2bf(c2.y); o[6] = f2bf(c2.z); o[7] = f2bf(c2.w);
        } else {
            int t = f >> 1, kk = f & 1;
            int d = t * 16 + l15;
            #pragma unroll
            for (int j = 0; j < 8; ++j) {
                int k = (2 * ((j >> 2) & 1) + kk) * 16 + l4 * 4 + (j & 3);
                o[j] = f2bf(vp[k * DHEAD + d]);
            }
        }
        *(u16x8*)(tb + c16 * 8) = o;
    }
    if (tid < KBLK)
        Mb[(size_t)tile * 64 + tid] =
            mask[(size_t)b * S_LEN + kt * KBLK + tid] ? -FM : -INFINITY;
}

// ---------------------------------------------------------------------------
// Phase 1: BARRIER-FREE + double-register-set prefetch. 1 wave/block, 16
// q-rows/wave. Frags for tile t+1 load into set B while computing tile t
// from set A (no LDS, no barriers, latency hidden by ILP). Static indexing
// via named A/B sets (no runtime-indexed arrays).
// ---------------------------------------------------------------------------
__global__ __launch_bounds__(64, 2) void attn_part(
        const float* __restrict__ Q, const unsigned short* __restrict__ Tb,
        const float* __restrict__ Mb,
        unsigned short* __restrict__ O_part, float* __restrict__ l_part, int Bn)
{
    const int blk = blockIdx.x;
    const int c   = blk & (NS - 1);
    const int qt  = 255 - ((blk >> 3) & 255);   // LPT: longest q-tiles first
    const int b   = blk >> 11;
    const int q0  = qt * 16;
    const int nt  = (q0 >> 6) + 1;              // causal k-tiles for this q-tile
    const int k0  = c * CSZ;
    if (k0 >= nt) return;                       // empty chunk
    const int k1  = (k0 + CSZ < nt) ? (k0 + CSZ) : nt;

    const int lane = threadIdx.x;
    const int l15 = lane & 15;
    const int l4 = lane >> 4;
    const int qg = q0 + l15;                    // this lane's q-row

    const float sc = 0.125f * 1.44269504088896340736f;  // 1/sqrt(D)*log2(e)

    // ---- Q fragments (B-operand): q-row = q0+l15, d = l4*8 + kk*32 ----
    bf16x8 qf[2];
    {
        const float* qp = Q + ((size_t)(b * S_LEN + qg)) * DHEAD + l4 * 8;
        #pragma unroll
        for (int kk = 0; kk < 2; ++kk) {
            float4 a = *(const float4*)(qp + kk * 32);
            float4 cq = *(const float4*)(qp + kk * 32 + 4);
            bf16x8 f;
            f[0] = (short)f2bf(a.x * sc); f[1] = (short)f2bf(a.y * sc);
            f[2] = (short)f2bf(a.z * sc); f[3] = (short)f2bf(a.w * sc);
            f[4] = (short)f2bf(cq.x * sc); f[5] = (short)f2bf(cq.y * sc);
            f[6] = (short)f2bf(cq.z * sc); f[7] = (short)f2bf(cq.w * sc);
            qf[kk] = f;
        }
    }

    f32x4 acc[4];
    #pragma unroll
    for (int t = 0; t < 4; ++t) acc[t] = (f32x4){0.f, 0.f, 0.f, 0.f};
    f32x4 lacc = (f32x4){0.f, 0.f, 0.f, 0.f};

    // ---- double register sets ----
    bf16x8 kfrA[8], vfrA[8], kfrB[8], vfrB[8];
    f32x4 biasA[4], biasB[4];

    auto LOADF = [&](int kt, bf16x8* kfr, bf16x8* vfr, f32x4* bias) {
        const unsigned short* tb = Tb + ((size_t)(b * 64 + kt)) * 8192 + lane * 8;
        const float* mbp = Mb + ((size_t)(b * 64 + kt)) * 64 + l4 * 4;
        #pragma unroll
        for (int f = 0; f < 8; ++f)
            kfr[f] = *(const bf16x8*)(tb + f * 512);
        #pragma unroll
        for (int f = 0; f < 8; ++f)
            vfr[f] = *(const bf16x8*)(tb + 4096 + f * 512);
        #pragma unroll
        for (int ct = 0; ct < 4; ++ct)
            bias[ct] = *(const f32x4*)(mbp + ct * 16);
    };

    auto COMPUTE = [&](int kt, const bf16x8* kfr, const bf16x8* vfr,
                       const f32x4* bias) {
        // ---- QK^T swapped: s[ct][i] = score(q=qg, k=kt*64+ct*16+l4*4+i) ----
        f32x4 s[4];
        __builtin_amdgcn_s_setprio(1);
        #pragma unroll
        for (int ct = 0; ct < 4; ++ct) {
            f32x4 z = (f32x4){0.f, 0.f, 0.f, 0.f};
            z = __builtin_amdgcn_mfma_f32_16x16x32_bf16(kfr[ct * 2 + 0], qf[0], z, 0, 0, 0);
            z = __builtin_amdgcn_mfma_f32_16x16x32_bf16(kfr[ct * 2 + 1], qf[1], z, 0, 0, 0);
            s[ct] = z;
        }
        __builtin_amdgcn_s_setprio(0);

        // ---- bias + causal + raw exp2, in-register ----
        const bool diag = (kt == nt - 1);
        f32x4 p[4];
        #pragma unroll
        for (int ct = 0; ct < 4; ++ct) {
            f32x4 v = s[ct] + bias[ct];
            if (diag) {
                int kb_ = kt * 64 + ct * 16 + l4 * 4;
                #pragma unroll
                for (int i = 0; i < 4; ++i)
                    if (kb_ + i > qg) v[i] = -INFINITY;
            }
            f32x4 pe;
            pe[0] = exp2_raw(v[0]); pe[1] = exp2_raw(v[1]);
            pe[2] = exp2_raw(v[2]); pe[3] = exp2_raw(v[3]);
            p[ct] = pe;
            lacc += pe;
        }

        // ---- pack P fragments (sigma order baked into V frags) ----
        bf16x8 pf[2];
        #pragma unroll
        for (int kk = 0; kk < 2; ++kk) {
            union { unsigned u[4]; bf16x8 v; } pk;
            pk.u[0] = pack_bf2(p[kk][0], p[kk][1]);
            pk.u[1] = pack_bf2(p[kk][2], p[kk][3]);
            pk.u[2] = pack_bf2(p[kk + 2][0], p[kk + 2][1]);
            pk.u[3] = pack_bf2(p[kk + 2][2], p[kk + 2][3]);
            pf[kk] = pk.v;
        }

        // ---- PV ----
        __builtin_amdgcn_s_setprio(1);
        #pragma unroll
        for (int kk = 0; kk < 2; ++kk) {
            #pragma unroll
            for (int t = 0; t < 4; ++t)
                acc[t] = __builtin_amdgcn_mfma_f32_16x16x32_bf16(
                    pf[kk], vfr[t * 2 + kk], acc[t], 0, 0, 0);
        }
        __builtin_amdgcn_s_setprio(0);
    };

    // ---- software-pipelined main loop (A/B sets, static names) ----
    LOADF(k0, kfrA, vfrA, biasA);
    for (int kt = k0; kt < k1; kt += 2) {
        if (kt + 1 < k1) LOADF(kt + 1, kfrB, vfrB, biasB);   // fly under A-compute
        COMPUTE(kt, kfrA, vfrA, biasA);
        if (kt + 1 < k1) {
            if (kt + 2 < k1) LOADF(kt + 2, kfrA, vfrA, biasA); // fly under B-compute
            COMPUTE(kt + 1, kfrB, vfrB, biasB);
        }
    }

    // ---- row denominator: lane owns q=qg slice; reduce across l4 group ----
    float la = lacc[0] + lacc[1] + lacc[2] + lacc[3];
    la += __shfl_xor(la, 16);
    la += __shfl_xor(la, 32);

    #pragma unroll
    for (int i = 0; i < 4; ++i) {
        int qr = q0 + l4 * 4 + i;
        size_t rb = ((size_t)c * Bn + b) * S_LEN + qr;
        unsigned short* op = O_part + rb * 64 + l15;
        #pragma unroll
        for (int t = 0; t < 4; ++t)
            op[t * 16] = f2bf(acc[t][i]);
    }
    if (l4 == 0) {
        size_t rb = ((size_t)c * Bn + b) * S_LEN + qg;
        l_part[rb] = la;
    }
}

// ---------------------------------------------------------------------------
// Phase 2: out = (sum_c O_c) / (sum_c l_c)   (bf16 partials)
// ---------------------------------------------------------------------------
__global__ __launch_bounds__(256) void attn_reduce(
        const unsigned short* __restrict__ O_part, const float* __restrict__ l_part,
        float* __restrict__ out, int Bn)
{
    int g = blockIdx.x * 4 + (threadIdx.x >> 6);
    int d = threadIdx.x & 63;
    int b = g >> 12;
    int q = g & (S_LEN - 1);
    int nc = (q >> 9) + 1;

    float den = 0.f, acc = 0.f;
    for (int cc = 0; cc < nc; ++cc) {
        size_t rb = ((size_t)cc * Bn + b) * S_LEN + q;
        den += l_part[rb];
        acc += bf2f(O_part[rb * 64 + d]);
    }
    out[((size_t)b * S_LEN + q) * 64 + d] = acc / den;
}

// ---------------------------------------------------------------------------
// Fallback: proven single-pass kernel (only if ws_size is insufficient)
// ---------------------------------------------------------------------------
__global__ __launch_bounds__(256) void attn_fwd(
        const float* __restrict__ Q, const float* __restrict__ K,
        const float* __restrict__ V, const int* __restrict__ mask,
        float* __restrict__ out)
{
    __shared__ __align__(16) unsigned short K_lds[KBLK * DHEAD];
    __shared__ __align__(16) unsigned short Vt_lds[DHEAD * KBLK];
    __shared__ __align__(16) unsigned short P_lds[4 * 16 * KBLK];
    __shared__ float mb[KBLK];

    const int tid = threadIdx.x;
    const int lane = tid & 63;
    const int wq = tid >> 6;
    const int l15 = lane & 15;
    const int l4 = lane >> 4;

    const int bq = blockIdx.x & 63;
    const int b  = blockIdx.x >> 6;
    const int q0 = bq * 64;
    const int nt = bq + 1;

    const float sc = 0.125f * 1.44269504088896340736f;

    bf16x8 qf[2];
    {
        const float* qp = Q + ((size_t)(b * S_LEN + q0 + wq * 16 + l15)) * DHEAD + l4 * 8;
        for (int kk = 0; kk < 2; ++kk) {
            float4 a = *(const float4*)(qp + kk * 32);
            float4 c = *(const float4*)(qp + kk * 32 + 4);
            bf16x8 f;
            f[0] = (short)f2bf(a.x * sc); f[1] = (short)f2bf(a.y * sc);
            f[2] = (short)f2bf(a.z * sc); f[3] = (short)f2bf(a.w * sc);
            f[4] = (short)f2bf(c.x * sc); f[5] = (short)f2bf(c.y * sc);
            f[6] = (short)f2bf(c.z * sc); f[7] = (short)f2bf(c.w * sc);
            qf[kk] = f;
        }
    }

    float4 kv[4];
    float4 vv[4];
    int    mreg;
    const int rp_  = (tid >> 4) << 1;
    const int d4v_ = (tid & 15) << 2;

    auto LOAD_TILE = [&](int kt) {
        const float* kp = K + ((size_t)(b * S_LEN + kt * KBLK)) * DHEAD;
        #pragma unroll
        for (int r = 0; r < 4; ++r) {
            int qi = tid + 256 * r;
            int kr = qi >> 4, d4 = (qi & 15) << 2;
            kv[r] = *(const float4*)(kp + kr * DHEAD + d4);
        }
        const float* vp = V + ((size_t)(b * S_LEN + kt * KBLK)) * DHEAD;
        #pragma unroll
        for (int r = 0; r < 2; ++r) {
            int row0 = rp_ + r * 32;
            vv[2 * r]     = *(const float4*)(vp + row0 * DHEAD + d4v_);
            vv[2 * r + 1] = *(const float4*)(vp + (row0 + 1) * DHEAD + d4v_);
        }
        mreg = mask[(size_t)b * S_LEN + kt * KBLK + (tid & 63)];
    };

    auto WRITE_TILE = [&]() {
        #pragma unroll
        for (int r = 0; r < 4; ++r) {
            int qi = tid + 256 * r;
            int kr = qi >> 4, d4 = (qi & 15) << 2;
            float4 v = kv[r];
            uint2 h;
            h.x = pack_bf2(v.x, v.y);
            h.y = pack_bf2(v.z, v.w);
            int byte = (kr * 128 + d4 * 2) ^ ((kr & 7) << 4);
            *(uint2*)((char*)K_lds + byte) = h;
        }
        #pragma unroll
        for (int r = 0; r < 2; ++r) {
            int row0 = rp_ + r * 32;
            float4 a = vv[2 * r];
            float4 c = vv[2 * r + 1];
            #pragma unroll
            for (int j = 0; j < 4; ++j) {
                int d = d4v_ + j;
                float aj = (j == 0) ? a.x : (j == 1) ? a.y : (j == 2) ? a.z : a.w;
                float cj = (j == 0) ? c.x : (j == 1) ? c.y : (j == 2) ? c.z : c.w;
                unsigned pack = pack_bf2(aj, cj);
                int byte = (d * 128 + row0 * 2) ^ ((d & 7) << 4);
                *(unsigned*)((char*)Vt_lds + byte) = pack;
            }
        }
        if (tid < KBLK)
            mb[tid] = mreg ? -FM : -INFINITY;
    };

    f32x4 acc[4];
    for (int t = 0; t < 4; ++t) acc[t] = (f32x4){0.f, 0.f, 0.f, 0.f};
    float l_acc[4] = {0.f, 0.f, 0.f, 0.f};

    LOAD_TILE(0);

    for (int kt = 0; kt < nt; ++kt) {
        __syncthreads();
        WRITE_TILE();
        __syncthreads();
        if (kt + 1 < nt) LOAD_TILE(kt + 1);

        f32x4 s[4];
        for (int ct = 0; ct < 4; ++ct) {
            f32x4 z = (f32x4){0.f, 0.f, 0.f, 0.f};
            for (int kk = 0; kk < 2; ++kk) {
                int row = ct * 16 + l15;
                int byte = (row * 128 + (l4 * 8 + kk * 32) * 2) ^ ((row & 7) << 4);
                bf16x8 kf = *(const bf16x8*)((const char*)K_lds + byte);
                z = __builtin_amdgcn_mfma_f32_16x16x32_bf16(qf[kk], kf, z, 0, 0, 0);
            }
            s[ct] = z;
        }

        const bool diag = (kt == nt - 1);
        for (int ct = 0; ct < 4; ++ct) {
            float bias = mb[ct * 16 + l15];
            int colg = kt * KBLK + ct * 16 + l15;
            for (int i = 0; i < 4; ++i) {
                float v = s[ct][i] + bias;
                if (diag) {
                    int qg2 = q0 + wq * 16 + l4 * 4 + i;
                    if (colg > qg2) v = -INFINITY;
                }
                float p = exp2_raw(v);
                l_acc[i] += p;
                int row = l4 * 4 + i;
                int col = ct * 16 + l15;
                int byte = (row * 128 + col * 2) ^ ((row & 7) << 4);
                *(unsigned short*)((char*)P_lds + wq * 2048 + byte) = f2bf(p);
            }
        }

        for (int kk = 0; kk < 2; ++kk) {
            int pbyte = (l15 * 128 + (l4 * 8 + kk * 32) * 2) ^ ((l15 & 7) << 4);
            bf16x8 pf = *(const bf16x8*)((const char*)P_lds + wq * 2048 + pbyte);
            for (int t = 0; t < 4; ++t) {
                int d = t * 16 + l15;
                int vbyte = (d * 128 + (l4 * 8 + kk * 32) * 2) ^ ((d & 7) << 4);
                bf16x8 vf = *(const bf16x8*)((const char*)Vt_lds + vbyte);
                acc[t] = __builtin_amdgcn_mfma_f32_16x16x32_bf16(pf, vf, acc[t], 0, 0, 0);
            }
        }
    }

    for (int i = 0; i < 4; ++i) {
        float v = l_acc[i];
        v += __shfl_xor(v, 1);
        v += __shfl_xor(v, 2);
        v += __shfl_xor(v, 4);
        v += __shfl_xor(v, 8);
        l_acc[i] = v;
    }

    for (int i = 0; i < 4; ++i) {
        float inv = 1.0f / l_acc[i];
        int qg2 = q0 + wq * 16 + l4 * 4 + i;
        float* op = out + ((size_t)(b * S_LEN + qg2)) * DHEAD + l15;
        for (int t = 0; t < 4; ++t)
            op[t * 16] = acc[t][i] * inv;
    }
}

extern "C" void kernel_launch(void* const* d_in, const int* in_sizes, int n_in,
                              void* d_out, int out_size, void* d_ws, size_t ws_size,
                              hipStream_t stream) {
    const float* Q = (const float*)d_in[0];
    const float* K = (const float*)d_in[1];
    const float* V = (const float*)d_in[2];
    const int* mask = (const int*)d_in[3];
    float* out = (float*)d_out;
    int Bn = in_sizes[0] / (S_LEN * DHEAD);

    size_t oN = (size_t)NS * Bn * S_LEN * 64;          // O_part ushorts
    size_t lN = (size_t)NS * Bn * S_LEN;               // l_part floats
    size_t tN = (size_t)Bn * 64 * 8192;                // blob ushorts
    size_t mN = (size_t)Bn * 64 * 64;                  // bias floats
    size_t need = oN * 2 + lN * 4 + tN * 2 + mN * 4;
    if (ws_size >= need) {
        unsigned short* O_part = (unsigned short*)d_ws;
        float* l_part = (float*)(O_part + oN);
        unsigned short* Tb = (unsigned short*)(l_part + lN);
        float* Mb = (float*)(Tb + tN);
        prep<<<dim3(Bn * 64), dim3(256), 0, stream>>>(K, V, mask, Tb, Mb);
        attn_part<<<dim3(Bn * 256 * NS), dim3(64), 0, stream>>>(
            Q, Tb, Mb, O_part, l_part, Bn);
        attn_reduce<<<dim3(Bn * S_LEN / 4), dim3(256), 0, stream>>>(
            O_part, l_part, out, Bn);
    } else {
        attn_fwd<<<dim3(Bn * 64), dim3(256), 0, stream>>>(Q, K, V, mask, out);
    }
}

// Round 19
// 50.650 us; speedup vs baseline: 1.2204x; 1.2204x over previous
//
#include <hip/hip_runtime.h>
#include <hip/hip_bf16.h>

#define S_LEN 4096
#define DHEAD 64
#define KBLK 64
#define CSZ 8          // k-tiles per chunk (512 kv positions)
#define NS 8           // max chunks per q-tile
#define FM 12.0f       // fixed softmax base (log2 domain); cancels in final divide

typedef __attribute__((ext_vector_type(8))) short bf16x8;
typedef __attribute__((ext_vector_type(8))) unsigned short u16x8;
typedef __attribute__((ext_vector_type(4))) float f32x4;

__device__ __forceinline__ unsigned short f2bf(float f) {
    union { float f; unsigned u; } v; v.f = f;
    unsigned r = v.u + 0x7fffu + ((v.u >> 16) & 1u);   // RNE
    return (unsigned short)(r >> 16);
}

__device__ __forceinline__ float bf2f(unsigned short h) {
    union { unsigned u; float f; } v; v.u = ((unsigned)h) << 16; return v.f;
}

__device__ __forceinline__ unsigned pack_bf2(float a, float b) {
    __hip_bfloat162 h = __float22bfloat162_rn(float2{a, b});
    union { __hip_bfloat162 h; unsigned u; } cv; cv.h = h;
    return cv.u;
}

// raw 2^x — v_exp_f32 (ISA §3). s_nop covers the TRANS-use hazard since the
// compiler's hazard recognizer may not scan inline asm. -inf -> 0 natively.
__device__ __forceinline__ float exp2_raw(float x) {
    float r;
    asm volatile("v_exp_f32 %0, %1\n\ts_nop 0" : "=v"(r) : "v"(x));
    return r;
}

// async global->LDS, 16B per lane; lds ptr is WAVE-UNIFORM base (HW adds lane*16)
__device__ __forceinline__ void gl_lds16(const void* g, void* l) {
    __builtin_amdgcn_global_load_lds(
        (const __attribute__((address_space(1))) void*)g,
        (__attribute__((address_space(3))) void*)l, 16, 0, 0);
}

// ---------------------------------------------------------------------------
// Prepass: build bf16 tile blobs = exact LDS images (swizzle + sigma baked in).
// K image byte: (kr*128 + d*2) ^ ((kr&7)<<4)
// V image byte: (d*128 + sig(k)*2) ^ (((d>>1)&7)<<4),
//   sig(k) = (ct&1)*32 + l4k*8 + (ct>>1)*4 + i  for k = ct*16 + l4k*4 + i
// ---------------------------------------------------------------------------
__global__ __launch_bounds__(256) void prep(
        const float* __restrict__ K, const float* __restrict__ V,
        unsigned short* __restrict__ Kb, unsigned short* __restrict__ Vb)
{
    const int tile = blockIdx.x;            // b*64 + kt
    const int b = tile >> 6, kt = tile & 63;
    const float* kp = K + ((size_t)(b * S_LEN + kt * KBLK)) * DHEAD;
    const float* vp = V + ((size_t)(b * S_LEN + kt * KBLK)) * DHEAD;
    unsigned short* kb = Kb + (size_t)tile * 4096;
    unsigned short* vb = Vb + (size_t)tile * 4096;
    const int tid = threadIdx.x;

    #pragma unroll
    for (int r = 0; r < 2; ++r) {
        int ci = r * 256 + tid;
        int base = ci * 16;                  // output byte
        int kr = base >> 7;
        int low = (base & 127) ^ ((kr & 7) << 4);
        int d0 = low >> 1;                   // 8 consecutive d
        u16x8 o;
        #pragma unroll
        for (int j = 0; j < 8; ++j) o[j] = f2bf(kp[kr * DHEAD + d0 + j]);
        *(u16x8*)(kb + ci * 8) = o;
    }
    #pragma unroll
    for (int r = 0; r < 2; ++r) {
        int ci = r * 256 + tid;
        int base = ci * 16;
        int d = base >> 7;
        int low = (base & 127) ^ (((d >> 1) & 7) << 4);
        int slot0 = low >> 1;                // multiple of 8
        u16x8 o;
        #pragma unroll
        for (int j = 0; j < 8; ++j) {
            int slot = slot0 + j;
            int ct = 2 * ((slot >> 2) & 1) + ((slot >> 5) & 1);
            int k = ct * 16 + ((slot >> 3) & 3) * 4 + (slot & 3);
            o[j] = f2bf(vp[k * DHEAD + d]);
        }
        *(u16x8*)(vb + ci * 8) = o;
    }
}

// ---------------------------------------------------------------------------
// Phase 1: swapped QK^T, in-register P, sigma-permuted V, blob staging via
// global_load_lds. Dbuf, 1 barrier/step. O partials bf16. Raw v_exp_f32.
// ---------------------------------------------------------------------------
__global__ __launch_bounds__(256) void attn_part(
        const float* __restrict__ Q, const unsigned short* __restrict__ Kb,
        const unsigned short* __restrict__ Vb, const int* __restrict__ mask,
        unsigned short* __restrict__ O_part, float* __restrict__ l_part, int Bn)
{
    __shared__ __align__(16) unsigned short K_lds[2][4096];
    __shared__ __align__(16) unsigned short V_lds[2][4096];
    __shared__ __align__(16) float mb[2][KBLK];

    const int blk = blockIdx.x;
    const int c   = blk & (NS - 1);
    const int bq  = 63 - ((blk >> 3) & 63);   // LPT
    const int b   = blk >> 9;
    const int nt  = bq + 1;
    const int k0  = c * CSZ;
    if (k0 >= nt) return;
    const int k1  = (k0 + CSZ < nt) ? (k0 + CSZ) : nt;

    const int tid = threadIdx.x;
    const int lane = tid & 63;
    const int wq = tid >> 6;
    const int l15 = lane & 15;
    const int l4 = lane >> 4;
    const int q0 = bq * 64;
    const int qg = q0 + wq * 16 + l15;

    const float sc = 0.125f * 1.44269504088896340736f;

    bf16x8 qf[2];
    {
        const float* qp = Q + ((size_t)(b * S_LEN + qg)) * DHEAD + l4 * 8;
        for (int kk = 0; kk < 2; ++kk) {
            float4 a = *(const float4*)(qp + kk * 32);
            float4 cq = *(const float4*)(qp + kk * 32 + 4);
            bf16x8 f;
            f[0] = (short)f2bf(a.x * sc); f[1] = (short)f2bf(a.y * sc);
            f[2] = (short)f2bf(a.z * sc); f[3] = (short)f2bf(a.w * sc);
            f[4] = (short)f2bf(cq.x * sc); f[5] = (short)f2bf(cq.y * sc);
            f[6] = (short)f2bf(cq.z * sc); f[7] = (short)f2bf(cq.w * sc);
            qf[kk] = f;
        }
    }

    int mreg;
    auto STAGE = [&](int kt, int buf) {
        const unsigned short* kb = Kb + ((size_t)(b * 64 + kt)) * 4096;
        const unsigned short* vb = Vb + ((size_t)(b * 64 + kt)) * 4096;
        #pragma unroll
        for (int r = 0; r < 2; ++r) {
            int ci = r * 256 + tid;
            int ub = (r * 256 + wq * 64) * 16;   // wave-uniform LDS byte base
            gl_lds16(kb + ci * 8, (char*)&K_lds[buf][0] + ub);
            gl_lds16(vb + ci * 8, (char*)&V_lds[buf][0] + ub);
        }
        mreg = mask[(size_t)b * S_LEN + kt * KBLK + lane];
    };

    f32x4 acc[4];
    for (int t = 0; t < 4; ++t) acc[t] = (f32x4){0.f, 0.f, 0.f, 0.f};
    f32x4 lacc = (f32x4){0.f, 0.f, 0.f, 0.f};

    STAGE(k0, 0);
    if (tid < KBLK) mb[0][tid] = mreg ? -FM : -INFINITY;
    __syncthreads();                       // drains gload_lds (vmcnt) + publishes
    int cur = 0;

    for (int kt = k0; kt < k1; ++kt) {
        const bool more = (kt + 1 < k1);
        if (more) STAGE(kt + 1, cur ^ 1);  // DMA flies under compute below

        // ---- QK^T swapped ----
        f32x4 s[4];
        __builtin_amdgcn_s_setprio(1);
        #pragma unroll
        for (int ct = 0; ct < 4; ++ct) {
            f32x4 z = (f32x4){0.f, 0.f, 0.f, 0.f};
            #pragma unroll
            for (int kk = 0; kk < 2; ++kk) {
                int row = ct * 16 + l15;
                int byte = (row * 128 + (l4 * 8 + kk * 32) * 2) ^ ((row & 7) << 4);
                bf16x8 kf = *(const bf16x8*)((const char*)&K_lds[cur][0] + byte);
                z = __builtin_amdgcn_mfma_f32_16x16x32_bf16(kf, qf[kk], z, 0, 0, 0);
            }
            s[ct] = z;
        }
        __builtin_amdgcn_s_setprio(0);

        // ---- bias + causal + raw exp2 in-register ----
        const bool diag = (kt == nt - 1);
        f32x4 p[4];
        #pragma unroll
        for (int ct = 0; ct < 4; ++ct) {
            f32x4 bias4 = *(const f32x4*)&mb[cur][ct * 16 + l4 * 4];
            f32x4 v = s[ct] + bias4;
            if (diag) {
                int kb_ = kt * 64 + ct * 16 + l4 * 4;
                #pragma unroll
                for (int i = 0; i < 4; ++i)
                    if (kb_ + i > qg) v[i] = -INFINITY;
            }
            f32x4 pe;
            pe[0] = exp2_raw(v[0]); pe[1] = exp2_raw(v[1]);
            pe[2] = exp2_raw(v[2]); pe[3] = exp2_raw(v[3]);
            p[ct] = pe;
            lacc += pe;
        }

        // ---- pack P fragments (matches sigma-permuted V) ----
        bf16x8 pf[2];
        #pragma unroll
        for (int kk = 0; kk < 2; ++kk) {
            union { unsigned u[4]; bf16x8 v; } pk;
            pk.u[0] = pack_bf2(p[kk][0], p[kk][1]);
            pk.u[1] = pack_bf2(p[kk][2], p[kk][3]);
            pk.u[2] = pack_bf2(p[kk + 2][0], p[kk + 2][1]);
            pk.u[3] = pack_bf2(p[kk + 2][2], p[kk + 2][3]);
            pf[kk] = pk.v;
        }

        // ---- PV ----
        __builtin_amdgcn_s_setprio(1);
        #pragma unroll
        for (int kk = 0; kk < 2; ++kk) {
            #pragma unroll
            for (int t = 0; t < 4; ++t) {
                int d = t * 16 + l15;
                int vbyte = (d * 128 + (l4 * 8 + kk * 32) * 2) ^ (((d >> 1) & 7) << 4);
                bf16x8 vf = *(const bf16x8*)((const char*)&V_lds[cur][0] + vbyte);
                acc[t] = __builtin_amdgcn_mfma_f32_16x16x32_bf16(pf[kk], vf, acc[t], 0, 0, 0);
            }
        }
        __builtin_amdgcn_s_setprio(0);

        if (more && tid < KBLK) mb[cur ^ 1][tid] = mreg ? -FM : -INFINITY;
        __syncthreads();                   // drains next-tile DMA + publishes
        cur ^= 1;
    }

    // ---- row denominator ----
    float la = lacc[0] + lacc[1] + lacc[2] + lacc[3];
    la += __shfl_xor(la, 16);
    la += __shfl_xor(la, 32);

    for (int i = 0; i < 4; ++i) {
        int qr = q0 + wq * 16 + l4 * 4 + i;
        size_t rb = ((size_t)c * Bn + b) * S_LEN + qr;
        unsigned short* op = O_part + rb * 64 + l15;
        #pragma unroll
        for (int t = 0; t < 4; ++t)
            op[t * 16] = f2bf(acc[t][i]);
    }
    if (l4 == 0) {
        size_t rb = ((size_t)c * Bn + b) * S_LEN + qg;
        l_part[rb] = la;
    }
}

// ---------------------------------------------------------------------------
// Phase 2: out = (sum_c O_c) / (sum_c l_c)   (bf16 partials)
// ---------------------------------------------------------------------------
__global__ __launch_bounds__(256) void attn_reduce(
        const unsigned short* __restrict__ O_part, const float* __restrict__ l_part,
        float* __restrict__ out, int Bn)
{
    int g = blockIdx.x * 4 + (threadIdx.x >> 6);
    int d = threadIdx.x & 63;
    int b = g >> 12;
    int q = g & (S_LEN - 1);
    int nc = (q >> 9) + 1;

    float den = 0.f, acc = 0.f;
    for (int cc = 0; cc < nc; ++cc) {
        size_t rb = ((size_t)cc * Bn + b) * S_LEN + q;
        den += l_part[rb];
        acc += bf2f(O_part[rb * 64 + d]);
    }
    out[((size_t)b * S_LEN + q) * 64 + d] = acc / den;
}

// ---------------------------------------------------------------------------
// Fallback: proven single-pass kernel (only if ws_size is insufficient)
// ---------------------------------------------------------------------------
__global__ __launch_bounds__(256) void attn_fwd(
        const float* __restrict__ Q, const float* __restrict__ K,
        const float* __restrict__ V, const int* __restrict__ mask,
        float* __restrict__ out)
{
    __shared__ __align__(16) unsigned short K_lds[KBLK * DHEAD];
    __shared__ __align__(16) unsigned short Vt_lds[DHEAD * KBLK];
    __shared__ __align__(16) unsigned short P_lds[4 * 16 * KBLK];
    __shared__ float mb[KBLK];

    const int tid = threadIdx.x;
    const int lane = tid & 63;
    const int wq = tid >> 6;
    const int l15 = lane & 15;
    const int l4 = lane >> 4;

    const int bq = blockIdx.x & 63;
    const int b  = blockIdx.x >> 6;
    const int q0 = bq * 64;
    const int nt = bq + 1;

    const float sc = 0.125f * 1.44269504088896340736f;

    bf16x8 qf[2];
    {
        const float* qp = Q + ((size_t)(b * S_LEN + q0 + wq * 16 + l15)) * DHEAD + l4 * 8;
        for (int kk = 0; kk < 2; ++kk) {
            float4 a = *(const float4*)(qp + kk * 32);
            float4 c = *(const float4*)(qp + kk * 32 + 4);
            bf16x8 f;
            f[0] = (short)f2bf(a.x * sc); f[1] = (short)f2bf(a.y * sc);
            f[2] = (short)f2bf(a.z * sc); f[3] = (short)f2bf(a.w * sc);
            f[4] = (short)f2bf(c.x * sc); f[5] = (short)f2bf(c.y * sc);
            f[6] = (short)f2bf(c.z * sc); f[7] = (short)f2bf(c.w * sc);
            qf[kk] = f;
        }
    }

    float4 kv[4];
    float4 vv[4];
    int    mreg;
    const int rp_  = (tid >> 4) << 1;
    const int d4v_ = (tid & 15) << 2;

    auto LOAD_TILE = [&](int kt) {
        const float* kp = K + ((size_t)(b * S_LEN + kt * KBLK)) * DHEAD;
        #pragma unroll
        for (int r = 0; r < 4; ++r) {
            int qi = tid + 256 * r;
            int kr = qi >> 4, d4 = (qi & 15) << 2;
            kv[r] = *(const float4*)(kp + kr * DHEAD + d4);
        }
        const float* vp = V + ((size_t)(b * S_LEN + kt * KBLK)) * DHEAD;
        #pragma unroll
        for (int r = 0; r < 2; ++r) {
            int row0 = rp_ + r * 32;
            vv[2 * r]     = *(const float4*)(vp + row0 * DHEAD + d4v_);
            vv[2 * r + 1] = *(const float4*)(vp + (row0 + 1) * DHEAD + d4v_);
        }
        mreg = mask[(size_t)b * S_LEN + kt * KBLK + (tid & 63)];
    };

    auto WRITE_TILE = [&]() {
        #pragma unroll
        for (int r = 0; r < 4; ++r) {
            int qi = tid + 256 * r;
            int kr = qi >> 4, d4 = (qi & 15) << 2;
            float4 v = kv[r];
            uint2 h;
            h.x = pack_bf2(v.x, v.y);
            h.y = pack_bf2(v.z, v.w);
            int byte = (kr * 128 + d4 * 2) ^ ((kr & 7) << 4);
            *(uint2*)((char*)K_lds + byte) = h;
        }
        #pragma unroll
        for (int r = 0; r < 2; ++r) {
            int row0 = rp_ + r * 32;
            float4 a = vv[2 * r];
            float4 c = vv[2 * r + 1];
            #pragma unroll
            for (int j = 0; j < 4; ++j) {
                int d = d4v_ + j;
                float aj = (j == 0) ? a.x : (j == 1) ? a.y : (j == 2) ? a.z : a.w;
                float cj = (j == 0) ? c.x : (j == 1) ? c.y : (j == 2) ? c.z : c.w;
                unsigned pack = pack_bf2(aj, cj);
                int byte = (d * 128 + row0 * 2) ^ ((d & 7) << 4);
                *(unsigned*)((char*)Vt_lds + byte) = pack;
            }
        }
        if (tid < KBLK)
            mb[tid] = mreg ? -FM : -INFINITY;
    };

    f32x4 acc[4];
    for (int t = 0; t < 4; ++t) acc[t] = (f32x4){0.f, 0.f, 0.f, 0.f};
    float l_acc[4] = {0.f, 0.f, 0.f, 0.f};

    LOAD_TILE(0);

    for (int kt = 0; kt < nt; ++kt) {
        __syncthreads();
        WRITE_TILE();
        __syncthreads();
        if (kt + 1 < nt) LOAD_TILE(kt + 1);

        f32x4 s[4];
        for (int ct = 0; ct < 4; ++ct) {
            f32x4 z = (f32x4){0.f, 0.f, 0.f, 0.f};
            for (int kk = 0; kk < 2; ++kk) {
                int row = ct * 16 + l15;
                int byte = (row * 128 + (l4 * 8 + kk * 32) * 2) ^ ((row & 7) << 4);
                bf16x8 kf = *(const bf16x8*)((const char*)K_lds + byte);
                z = __builtin_amdgcn_mfma_f32_16x16x32_bf16(qf[kk], kf, z, 0, 0, 0);
            }
            s[ct] = z;
        }

        const bool diag = (kt == nt - 1);
        for (int ct = 0; ct < 4; ++ct) {
            float bias = mb[ct * 16 + l15];
            int colg = kt * KBLK + ct * 16 + l15;
            for (int i = 0; i < 4; ++i) {
                float v = s[ct][i] + bias;
                if (diag) {
                    int qg2 = q0 + wq * 16 + l4 * 4 + i;
                    if (colg > qg2) v = -INFINITY;
                }
                float p = exp2_raw(v);
                l_acc[i] += p;
                int row = l4 * 4 + i;
                int col = ct * 16 + l15;
                int byte = (row * 128 + col * 2) ^ ((row & 7) << 4);
                *(unsigned short*)((char*)P_lds + wq * 2048 + byte) = f2bf(p);
            }
        }

        for (int kk = 0; kk < 2; ++kk) {
            int pbyte = (l15 * 128 + (l4 * 8 + kk * 32) * 2) ^ ((l15 & 7) << 4);
            bf16x8 pf = *(const bf16x8*)((const char*)P_lds + wq * 2048 + pbyte);
            for (int t = 0; t < 4; ++t) {
                int d = t * 16 + l15;
                int vbyte = (d * 128 + (l4 * 8 + kk * 32) * 2) ^ ((d & 7) << 4);
                bf16x8 vf = *(const bf16x8*)((const char*)Vt_lds + vbyte);
                acc[t] = __builtin_amdgcn_mfma_f32_16x16x32_bf16(pf, vf, acc[t], 0, 0, 0);
            }
        }
    }

    for (int i = 0; i < 4; ++i) {
        float v = l_acc[i];
        v += __shfl_xor(v, 1);
        v += __shfl_xor(v, 2);
        v += __shfl_xor(v, 4);
        v += __shfl_xor(v, 8);
        l_acc[i] = v;
    }

    for (int i = 0; i < 4; ++i) {
        float inv = 1.0f / l_acc[i];
        int qg2 = q0 + wq * 16 + l4 * 4 + i;
        float* op = out + ((size_t)(b * S_LEN + qg2)) * DHEAD + l15;
        for (int t = 0; t < 4; ++t)
            op[t * 16] = acc[t][i] * inv;
    }
}

extern "C" void kernel_launch(void* const* d_in, const int* in_sizes, int n_in,
                              void* d_out, int out_size, void* d_ws, size_t ws_size,
                              hipStream_t stream) {
    const float* Q = (const float*)d_in[0];
    const float* K = (const float*)d_in[1];
    const float* V = (const float*)d_in[2];
    const int* mask = (const int*)d_in[3];
    float* out = (float*)d_out;
    int Bn = in_sizes[0] / (S_LEN * DHEAD);

    size_t oN = (size_t)NS * Bn * S_LEN * 64;          // O_part ushorts
    size_t lN = (size_t)NS * Bn * S_LEN;               // l_part floats
    size_t bN = (size_t)Bn * 64 * 4096;                // blob ushorts (each)
    size_t need = oN * 2 + lN * 4 + bN * 2 * 2;
    if (ws_size >= need) {
        unsigned short* O_part = (unsigned short*)d_ws;
        float* l_part = (float*)(O_part + oN);
        unsigned short* Kb = (unsigned short*)(l_part + lN);
        unsigned short* Vb = Kb + bN;
        prep<<<dim3(Bn * 64), dim3(256), 0, stream>>>(K, V, Kb, Vb);
        attn_part<<<dim3(Bn * 64 * NS), dim3(256), 0, stream>>>(
            Q, Kb, Vb, mask, O_part, l_part, Bn);
        attn_reduce<<<dim3(Bn * S_LEN / 4), dim3(256), 0, stream>>>(
            O_part, l_part, out, Bn);
    } else {
        attn_fwd<<<dim3(Bn * 64), dim3(256), 0, stream>>>(Q, K, V, mask, out);
    }
}

// Round 20
// 48.216 us; speedup vs baseline: 1.2820x; 1.0505x over previous
//
#include <hip/hip_runtime.h>
#include <hip/hip_bf16.h>

#define S_LEN 4096
#define DHEAD 64
#define KBLK 64
#define CSZ 8          // k-tiles per chunk (512 kv positions)
#define NS 8           // max chunks per q-tile
#define FM 12.0f       // fixed softmax base (log2 domain); cancels in final divide

typedef __attribute__((ext_vector_type(8))) short bf16x8;
typedef __attribute__((ext_vector_type(8))) unsigned short u16x8;
typedef __attribute__((ext_vector_type(4))) float f32x4;

__device__ __forceinline__ unsigned short f2bf(float f) {
    union { float f; unsigned u; } v; v.f = f;
    unsigned r = v.u + 0x7fffu + ((v.u >> 16) & 1u);   // RNE
    return (unsigned short)(r >> 16);
}

__device__ __forceinline__ float bf2f(unsigned short h) {
    union { unsigned u; float f; } v; v.u = ((unsigned)h) << 16; return v.f;
}

__device__ __forceinline__ unsigned pack_bf2(float a, float b) {
    __hip_bfloat162 h = __float22bfloat162_rn(float2{a, b});
    union { __hip_bfloat162 h; unsigned u; } cv; cv.h = h;
    return cv.u;
}

// raw 2^x — v_exp_f32 (ISA §3). s_nop covers the TRANS-use hazard since the
// compiler's hazard recognizer may not scan inline asm. -inf -> 0 natively.
__device__ __forceinline__ float exp2_raw(float x) {
    float r;
    asm volatile("v_exp_f32 %0, %1\n\ts_nop 0" : "=v"(r) : "v"(x));
    return r;
}

// async global->LDS, 16B per lane; lds ptr is WAVE-UNIFORM base (HW adds lane*16)
__device__ __forceinline__ void gl_lds16(const void* g, void* l) {
    __builtin_amdgcn_global_load_lds(
        (const __attribute__((address_space(1))) void*)g,
        (__attribute__((address_space(3))) void*)l, 16, 0, 0);
}

// ---------------------------------------------------------------------------
// Prepass: build bf16 tile blobs = exact LDS images (swizzle + sigma baked in).
// K image byte: (kr*128 + d*2) ^ ((kr&7)<<4)
// V image byte: (d*128 + sig(k)*2) ^ (((d>>1)&7)<<4),
//   sig(k) = (ct&1)*32 + l4k*8 + (ct>>1)*4 + i  for k = ct*16 + l4k*4 + i
// V gather now goes through LDS (coalesced global reads, pad-65 kills bank
// conflicts); K path already coalesced.
// ---------------------------------------------------------------------------
__global__ __launch_bounds__(256) void prep(
        const float* __restrict__ K, const float* __restrict__ V,
        unsigned short* __restrict__ Kb, unsigned short* __restrict__ Vb)
{
    __shared__ float Vlds[64 * 65];         // [k][d], stride 65 (pad)

    const int tile = blockIdx.x;            // b*64 + kt
    const int b = tile >> 6, kt = tile & 63;
    const float* kp = K + ((size_t)(b * S_LEN + kt * KBLK)) * DHEAD;
    const float* vp = V + ((size_t)(b * S_LEN + kt * KBLK)) * DHEAD;
    unsigned short* kb = Kb + (size_t)tile * 4096;
    unsigned short* vb = Vb + (size_t)tile * 4096;
    const int tid = threadIdx.x;

    // ---- stage V tile into LDS, coalesced float4 reads ----
    #pragma unroll
    for (int r = 0; r < 4; ++r) {
        int idx = (r * 256 + tid) * 4;       // flat fp32 index 0..4095
        int k = idx >> 6, d = idx & 63;
        float4 v = *(const float4*)(vp + idx);
        Vlds[k * 65 + d]     = v.x;
        Vlds[k * 65 + d + 1] = v.y;
        Vlds[k * 65 + d + 2] = v.z;
        Vlds[k * 65 + d + 3] = v.w;
    }
    __syncthreads();

    // ---- K blob (coalesced global reads, unchanged) ----
    #pragma unroll
    for (int r = 0; r < 2; ++r) {
        int ci = r * 256 + tid;
        int base = ci * 16;                  // output byte
        int kr = base >> 7;
        int low = (base & 127) ^ ((kr & 7) << 4);
        int d0 = low >> 1;                   // 8 consecutive d
        u16x8 o;
        #pragma unroll
        for (int j = 0; j < 8; ++j) o[j] = f2bf(kp[kr * DHEAD + d0 + j]);
        *(u16x8*)(kb + ci * 8) = o;
    }
    // ---- V blob from LDS (gather now cheap) ----
    #pragma unroll
    for (int r = 0; r < 2; ++r) {
        int ci = r * 256 + tid;
        int base = ci * 16;
        int d = base >> 7;
        int low = (base & 127) ^ (((d >> 1) & 7) << 4);
        int slot0 = low >> 1;                // multiple of 8
        u16x8 o;
        #pragma unroll
        for (int j = 0; j < 8; ++j) {
            int slot = slot0 + j;
            int ct = 2 * ((slot >> 2) & 1) + ((slot >> 5) & 1);
            int k = ct * 16 + ((slot >> 3) & 3) * 4 + (slot & 3);
            o[j] = f2bf(Vlds[k * 65 + d]);
        }
        *(u16x8*)(vb + ci * 8) = o;
    }
}

// ---------------------------------------------------------------------------
// Phase 1: swapped QK^T, in-register P, sigma-permuted V, blob staging via
// global_load_lds. Dbuf, 1 barrier/step. O partials bf16. Raw v_exp_f32.
// (byte-identical to the verified 50.65 us kernel)
// ---------------------------------------------------------------------------
__global__ __launch_bounds__(256) void attn_part(
        const float* __restrict__ Q, const unsigned short* __restrict__ Kb,
        const unsigned short* __restrict__ Vb, const int* __restrict__ mask,
        unsigned short* __restrict__ O_part, float* __restrict__ l_part, int Bn)
{
    __shared__ __align__(16) unsigned short K_lds[2][4096];
    __shared__ __align__(16) unsigned short V_lds[2][4096];
    __shared__ __align__(16) float mb[2][KBLK];

    const int blk = blockIdx.x;
    const int c   = blk & (NS - 1);
    const int bq  = 63 - ((blk >> 3) & 63);   // LPT
    const int b   = blk >> 9;
    const int nt  = bq + 1;
    const int k0  = c * CSZ;
    if (k0 >= nt) return;
    const int k1  = (k0 + CSZ < nt) ? (k0 + CSZ) : nt;

    const int tid = threadIdx.x;
    const int lane = tid & 63;
    const int wq = tid >> 6;
    const int l15 = lane & 15;
    const int l4 = lane >> 4;
    const int q0 = bq * 64;
    const int qg = q0 + wq * 16 + l15;

    const float sc = 0.125f * 1.44269504088896340736f;

    bf16x8 qf[2];
    {
        const float* qp = Q + ((size_t)(b * S_LEN + qg)) * DHEAD + l4 * 8;
        for (int kk = 0; kk < 2; ++kk) {
            float4 a = *(const float4*)(qp + kk * 32);
            float4 cq = *(const float4*)(qp + kk * 32 + 4);
            bf16x8 f;
            f[0] = (short)f2bf(a.x * sc); f[1] = (short)f2bf(a.y * sc);
            f[2] = (short)f2bf(a.z * sc); f[3] = (short)f2bf(a.w * sc);
            f[4] = (short)f2bf(cq.x * sc); f[5] = (short)f2bf(cq.y * sc);
            f[6] = (short)f2bf(cq.z * sc); f[7] = (short)f2bf(cq.w * sc);
            qf[kk] = f;
        }
    }

    int mreg;
    auto STAGE = [&](int kt, int buf) {
        const unsigned short* kb = Kb + ((size_t)(b * 64 + kt)) * 4096;
        const unsigned short* vb = Vb + ((size_t)(b * 64 + kt)) * 4096;
        #pragma unroll
        for (int r = 0; r < 2; ++r) {
            int ci = r * 256 + tid;
            int ub = (r * 256 + wq * 64) * 16;   // wave-uniform LDS byte base
            gl_lds16(kb + ci * 8, (char*)&K_lds[buf][0] + ub);
            gl_lds16(vb + ci * 8, (char*)&V_lds[buf][0] + ub);
        }
        mreg = mask[(size_t)b * S_LEN + kt * KBLK + lane];
    };

    f32x4 acc[4];
    for (int t = 0; t < 4; ++t) acc[t] = (f32x4){0.f, 0.f, 0.f, 0.f};
    f32x4 lacc = (f32x4){0.f, 0.f, 0.f, 0.f};

    STAGE(k0, 0);
    if (tid < KBLK) mb[0][tid] = mreg ? -FM : -INFINITY;
    __syncthreads();                       // drains gload_lds (vmcnt) + publishes
    int cur = 0;

    for (int kt = k0; kt < k1; ++kt) {
        const bool more = (kt + 1 < k1);
        if (more) STAGE(kt + 1, cur ^ 1);  // DMA flies under compute below

        // ---- QK^T swapped ----
        f32x4 s[4];
        __builtin_amdgcn_s_setprio(1);
        #pragma unroll
        for (int ct = 0; ct < 4; ++ct) {
            f32x4 z = (f32x4){0.f, 0.f, 0.f, 0.f};
            #pragma unroll
            for (int kk = 0; kk < 2; ++kk) {
                int row = ct * 16 + l15;
                int byte = (row * 128 + (l4 * 8 + kk * 32) * 2) ^ ((row & 7) << 4);
                bf16x8 kf = *(const bf16x8*)((const char*)&K_lds[cur][0] + byte);
                z = __builtin_amdgcn_mfma_f32_16x16x32_bf16(kf, qf[kk], z, 0, 0, 0);
            }
            s[ct] = z;
        }
        __builtin_amdgcn_s_setprio(0);

        // ---- bias + causal + raw exp2 in-register ----
        const bool diag = (kt == nt - 1);
        f32x4 p[4];
        #pragma unroll
        for (int ct = 0; ct < 4; ++ct) {
            f32x4 bias4 = *(const f32x4*)&mb[cur][ct * 16 + l4 * 4];
            f32x4 v = s[ct] + bias4;
            if (diag) {
                int kb_ = kt * 64 + ct * 16 + l4 * 4;
                #pragma unroll
                for (int i = 0; i < 4; ++i)
                    if (kb_ + i > qg) v[i] = -INFINITY;
            }
            f32x4 pe;
            pe[0] = exp2_raw(v[0]); pe[1] = exp2_raw(v[1]);
            pe[2] = exp2_raw(v[2]); pe[3] = exp2_raw(v[3]);
            p[ct] = pe;
            lacc += pe;
        }

        // ---- pack P fragments (matches sigma-permuted V) ----
        bf16x8 pf[2];
        #pragma unroll
        for (int kk = 0; kk < 2; ++kk) {
            union { unsigned u[4]; bf16x8 v; } pk;
            pk.u[0] = pack_bf2(p[kk][0], p[kk][1]);
            pk.u[1] = pack_bf2(p[kk][2], p[kk][3]);
            pk.u[2] = pack_bf2(p[kk + 2][0], p[kk + 2][1]);
            pk.u[3] = pack_bf2(p[kk + 2][2], p[kk + 2][3]);
            pf[kk] = pk.v;
        }

        // ---- PV ----
        __builtin_amdgcn_s_setprio(1);
        #pragma unroll
        for (int kk = 0; kk < 2; ++kk) {
            #pragma unroll
            for (int t = 0; t < 4; ++t) {
                int d = t * 16 + l15;
                int vbyte = (d * 128 + (l4 * 8 + kk * 32) * 2) ^ (((d >> 1) & 7) << 4);
                bf16x8 vf = *(const bf16x8*)((const char*)&V_lds[cur][0] + vbyte);
                acc[t] = __builtin_amdgcn_mfma_f32_16x16x32_bf16(pf[kk], vf, acc[t], 0, 0, 0);
            }
        }
        __builtin_amdgcn_s_setprio(0);

        if (more && tid < KBLK) mb[cur ^ 1][tid] = mreg ? -FM : -INFINITY;
        __syncthreads();                   // drains next-tile DMA + publishes
        cur ^= 1;
    }

    // ---- row denominator ----
    float la = lacc[0] + lacc[1] + lacc[2] + lacc[3];
    la += __shfl_xor(la, 16);
    la += __shfl_xor(la, 32);

    for (int i = 0; i < 4; ++i) {
        int qr = q0 + wq * 16 + l4 * 4 + i;
        size_t rb = ((size_t)c * Bn + b) * S_LEN + qr;
        unsigned short* op = O_part + rb * 64 + l15;
        #pragma unroll
        for (int t = 0; t < 4; ++t)
            op[t * 16] = f2bf(acc[t][i]);
    }
    if (l4 == 0) {
        size_t rb = ((size_t)c * Bn + b) * S_LEN + qg;
        l_part[rb] = la;
    }
}

// ---------------------------------------------------------------------------
// Phase 2: out = (sum_c O_c) / (sum_c l_c)   (bf16 partials)
// Vectorized: thread owns a 4-wide d-quad of one row; uint2 loads, float4 store.
// ---------------------------------------------------------------------------
__global__ __launch_bounds__(256) void attn_reduce(
        const unsigned short* __restrict__ O_part, const float* __restrict__ l_part,
        float* __restrict__ out, int Bn)
{
    int g = blockIdx.x * 256 + threadIdx.x;        // global quad index
    int row = g >> 4;                              // Bn*S_LEN rows
    int qd  = (g & 15) * 4;                        // d-quad base
    int b = row >> 12;                             // S_LEN = 4096
    int q = row & (S_LEN - 1);
    int nc = (q >> 9) + 1;                         // chunks covering k <= q

    float den = 0.f;
    f32x4 acc = (f32x4){0.f, 0.f, 0.f, 0.f};
    for (int cc = 0; cc < nc; ++cc) {
        size_t rb = ((size_t)cc * Bn + b) * S_LEN + q;
        den += l_part[rb];
        uint2 u = *(const uint2*)(O_part + rb * 64 + qd);
        acc[0] += bf2f((unsigned short)(u.x & 0xffff));
        acc[1] += bf2f((unsigned short)(u.x >> 16));
        acc[2] += bf2f((unsigned short)(u.y & 0xffff));
        acc[3] += bf2f((unsigned short)(u.y >> 16));
    }
    float inv = 1.0f / den;
    float4 o;
    o.x = acc[0] * inv; o.y = acc[1] * inv;
    o.z = acc[2] * inv; o.w = acc[3] * inv;
    *(float4*)(out + ((size_t)b * S_LEN + q) * 64 + qd) = o;
}

// ---------------------------------------------------------------------------
// Fallback: proven single-pass kernel (only if ws_size is insufficient)
// ---------------------------------------------------------------------------
__global__ __launch_bounds__(256) void attn_fwd(
        const float* __restrict__ Q, const float* __restrict__ K,
        const float* __restrict__ V, const int* __restrict__ mask,
        float* __restrict__ out)
{
    __shared__ __align__(16) unsigned short K_lds[KBLK * DHEAD];
    __shared__ __align__(16) unsigned short Vt_lds[DHEAD * KBLK];
    __shared__ __align__(16) unsigned short P_lds[4 * 16 * KBLK];
    __shared__ float mb[KBLK];

    const int tid = threadIdx.x;
    const int lane = tid & 63;
    const int wq = tid >> 6;
    const int l15 = lane & 15;
    const int l4 = lane >> 4;

    const int bq = blockIdx.x & 63;
    const int b  = blockIdx.x >> 6;
    const int q0 = bq * 64;
    const int nt = bq + 1;

    const float sc = 0.125f * 1.44269504088896340736f;

    bf16x8 qf[2];
    {
        const float* qp = Q + ((size_t)(b * S_LEN + q0 + wq * 16 + l15)) * DHEAD + l4 * 8;
        for (int kk = 0; kk < 2; ++kk) {
            float4 a = *(const float4*)(qp + kk * 32);
            float4 c = *(const float4*)(qp + kk * 32 + 4);
            bf16x8 f;
            f[0] = (short)f2bf(a.x * sc); f[1] = (short)f2bf(a.y * sc);
            f[2] = (short)f2bf(a.z * sc); f[3] = (short)f2bf(a.w * sc);
            f[4] = (short)f2bf(c.x * sc); f[5] = (short)f2bf(c.y * sc);
            f[6] = (short)f2bf(c.z * sc); f[7] = (short)f2bf(c.w * sc);
            qf[kk] = f;
        }
    }

    float4 kv[4];
    float4 vv[4];
    int    mreg;
    const int rp_  = (tid >> 4) << 1;
    const int d4v_ = (tid & 15) << 2;

    auto LOAD_TILE = [&](int kt) {
        const float* kp = K + ((size_t)(b * S_LEN + kt * KBLK)) * DHEAD;
        #pragma unroll
        for (int r = 0; r < 4; ++r) {
            int qi = tid + 256 * r;
            int kr = qi >> 4, d4 = (qi & 15) << 2;
            kv[r] = *(const float4*)(kp + kr * DHEAD + d4);
        }
        const float* vp = V + ((size_t)(b * S_LEN + kt * KBLK)) * DHEAD;
        #pragma unroll
        for (int r = 0; r < 2; ++r) {
            int row0 = rp_ + r * 32;
            vv[2 * r]     = *(const float4*)(vp + row0 * DHEAD + d4v_);
            vv[2 * r + 1] = *(const float4*)(vp + (row0 + 1) * DHEAD + d4v_);
        }
        mreg = mask[(size_t)b * S_LEN + kt * KBLK + (tid & 63)];
    };

    auto WRITE_TILE = [&]() {
        #pragma unroll
        for (int r = 0; r < 4; ++r) {
            int qi = tid + 256 * r;
            int kr = qi >> 4, d4 = (qi & 15) << 2;
            float4 v = kv[r];
            uint2 h;
            h.x = pack_bf2(v.x, v.y);
            h.y = pack_bf2(v.z, v.w);
            int byte = (kr * 128 + d4 * 2) ^ ((kr & 7) << 4);
            *(uint2*)((char*)K_lds + byte) = h;
        }
        #pragma unroll
        for (int r = 0; r < 2; ++r) {
            int row0 = rp_ + r * 32;
            float4 a = vv[2 * r];
            float4 c = vv[2 * r + 1];
            #pragma unroll
            for (int j = 0; j < 4; ++j) {
                int d = d4v_ + j;
                float aj = (j == 0) ? a.x : (j == 1) ? a.y : (j == 2) ? a.z : a.w;
                float cj = (j == 0) ? c.x : (j == 1) ? c.y : (j == 2) ? c.z : c.w;
                unsigned pack = pack_bf2(aj, cj);
                int byte = (d * 128 + row0 * 2) ^ ((d & 7) << 4);
                *(unsigned*)((char*)Vt_lds + byte) = pack;
            }
        }
        if (tid < KBLK)
            mb[tid] = mreg ? -FM : -INFINITY;
    };

    f32x4 acc[4];
    for (int t = 0; t < 4; ++t) acc[t] = (f32x4){0.f, 0.f, 0.f, 0.f};
    float l_acc[4] = {0.f, 0.f, 0.f, 0.f};

    LOAD_TILE(0);

    for (int kt = 0; kt < nt; ++kt) {
        __syncthreads();
        WRITE_TILE();
        __syncthreads();
        if (kt + 1 < nt) LOAD_TILE(kt + 1);

        f32x4 s[4];
        for (int ct = 0; ct < 4; ++ct) {
            f32x4 z = (f32x4){0.f, 0.f, 0.f, 0.f};
            for (int kk = 0; kk < 2; ++kk) {
                int row = ct * 16 + l15;
                int byte = (row * 128 + (l4 * 8 + kk * 32) * 2) ^ ((row & 7) << 4);
                bf16x8 kf = *(const bf16x8*)((const char*)K_lds + byte);
                z = __builtin_amdgcn_mfma_f32_16x16x32_bf16(qf[kk], kf, z, 0, 0, 0);
            }
            s[ct] = z;
        }

        const bool diag = (kt == nt - 1);
        for (int ct = 0; ct < 4; ++ct) {
            float bias = mb[ct * 16 + l15];
            int colg = kt * KBLK + ct * 16 + l15;
            for (int i = 0; i < 4; ++i) {
                float v = s[ct][i] + bias;
                if (diag) {
                    int qg2 = q0 + wq * 16 + l4 * 4 + i;
                    if (colg > qg2) v = -INFINITY;
                }
                float p = exp2_raw(v);
                l_acc[i] += p;
                int row = l4 * 4 + i;
                int col = ct * 16 + l15;
                int byte = (row * 128 + col * 2) ^ ((row & 7) << 4);
                *(unsigned short*)((char*)P_lds + wq * 2048 + byte) = f2bf(p);
            }
        }

        for (int kk = 0; kk < 2; ++kk) {
            int pbyte = (l15 * 128 + (l4 * 8 + kk * 32) * 2) ^ ((l15 & 7) << 4);
            bf16x8 pf = *(const bf16x8*)((const char*)P_lds + wq * 2048 + pbyte);
            for (int t = 0; t < 4; ++t) {
                int d = t * 16 + l15;
                int vbyte = (d * 128 + (l4 * 8 + kk * 32) * 2) ^ ((d & 7) << 4);
                bf16x8 vf = *(const bf16x8*)((const char*)Vt_lds + vbyte);
                acc[t] = __builtin_amdgcn_mfma_f32_16x16x32_bf16(pf, vf, acc[t], 0, 0, 0);
            }
        }
    }

    for (int i = 0; i < 4; ++i) {
        float v = l_acc[i];
        v += __shfl_xor(v, 1);
        v += __shfl_xor(v, 2);
        v += __shfl_xor(v, 4);
        v += __shfl_xor(v, 8);
        l_acc[i] = v;
    }

    for (int i = 0; i < 4; ++i) {
        float inv = 1.0f / l_acc[i];
        int qg2 = q0 + wq * 16 + l4 * 4 + i;
        float* op = out + ((size_t)(b * S_LEN + qg2)) * DHEAD + l15;
        for (int t = 0; t < 4; ++t)
            op[t * 16] = acc[t][i] * inv;
    }
}

extern "C" void kernel_launch(void* const* d_in, const int* in_sizes, int n_in,
                              void* d_out, int out_size, void* d_ws, size_t ws_size,
                              hipStream_t stream) {
    const float* Q = (const float*)d_in[0];
    const float* K = (const float*)d_in[1];
    const float* V = (const float*)d_in[2];
    const int* mask = (const int*)d_in[3];
    float* out = (float*)d_out;
    int Bn = in_sizes[0] / (S_LEN * DHEAD);

    size_t oN = (size_t)NS * Bn * S_LEN * 64;          // O_part ushorts
    size_t lN = (size_t)NS * Bn * S_LEN;               // l_part floats
    size_t bN = (size_t)Bn * 64 * 4096;                // blob ushorts (each)
    size_t need = oN * 2 + lN * 4 + bN * 2 * 2;
    if (ws_size >= need) {
        unsigned short* O_part = (unsigned short*)d_ws;
        float* l_part = (float*)(O_part + oN);
        unsigned short* Kb = (unsigned short*)(l_part + lN);
        unsigned short* Vb = Kb + bN;
        prep<<<dim3(Bn * 64), dim3(256), 0, stream>>>(K, V, Kb, Vb);
        attn_part<<<dim3(Bn * 64 * NS), dim3(256), 0, stream>>>(
            Q, Kb, Vb, mask, O_part, l_part, Bn);
        attn_reduce<<<dim3(Bn * S_LEN * 16 / 256), dim3(256), 0, stream>>>(
            O_part, l_part, out, Bn);
    } else {
        attn_fwd<<<dim3(Bn * 64), dim3(256), 0, stream>>>(Q, K, V, mask, out);
    }
}